// Round 1
// baseline (362.789 us; speedup 1.0000x reference)
//
#include <hip/hip_runtime.h>
#include <hip/hip_bf16.h>
#include <cstddef>

typedef __bf16 bf16x8 __attribute__((ext_vector_type(8)));
typedef float f32x4 __attribute__((ext_vector_type(4)));

// ---------------- prep kernels ----------------

// x fp32 NCHW [8,512,8,8] -> bf16 NHWC [8,8,8,512]
__global__ void convert_x_kernel(const float* __restrict__ x, __hip_bfloat16* __restrict__ act0) {
    int t = blockIdx.x * 256 + threadIdx.x;          // 262144 total
    int c = t & 511; int rest = t >> 9;
    int w = rest & 7; rest >>= 3; int h = rest & 7; int b = rest >> 3;
    act0[t] = __float2bfloat16(x[((b * 512 + c) * 8 + h) * 8 + w]);
}

// W fp32 [CO][CI][3][3] -> bf16 [9][CO][CI]
__global__ void wtrans_kernel(const float* __restrict__ w, __hip_bfloat16* __restrict__ o,
                              int CO, int CI) {
    int t = blockIdx.x * 256 + threadIdx.x;
    int total = 9 * CO * CI;
    if (t >= total) return;
    int ci = t % CI; int r2 = t / CI; int co = r2 % CO; int tap = r2 / CO;
    o[t] = __float2bfloat16(w[(co * CI + ci) * 9 + tap]);
}

// wf fp32 [3][64][3][3] -> bf16 [9][16][64], rows 3..15 zeroed
__global__ void wtrans_final_kernel(const float* __restrict__ w, __hip_bfloat16* __restrict__ o) {
    int t = blockIdx.x * 256 + threadIdx.x;          // 9216 total
    int ci = t & 63; int r2 = t >> 6; int co = r2 & 15; int tap = r2 >> 4;
    float v = (co < 3) ? w[(co * 64 + ci) * 9 + tap] : 0.f;
    o[t] = __float2bfloat16(v);
}

// S[b][o] = style[b,:] . fw[o,:] + fb[o]; one wave per (b,o)
__global__ void style_fc_kernel(const float* __restrict__ style, const float* __restrict__ fw,
                                const float* __restrict__ fb, float* __restrict__ S, int CO) {
    int wv = threadIdx.x >> 6, lane = threadIdx.x & 63;
    int idx = blockIdx.x * 4 + wv;                   // idx < 8*CO by grid construction
    int b = idx / CO, o = idx - b * CO;
    const float* sb = style + b * 512;
    const float* fwo = fw + o * 512;
    float p = 0.f;
    #pragma unroll
    for (int k = lane; k < 512; k += 64) p += sb[k] * fwo[k];
    #pragma unroll
    for (int off = 32; off > 0; off >>= 1) p += __shfl_down(p, off);
    if (lane == 0) S[idx] = p + fb[o];
}

// ---------------- fused upsample+conv+scale+relu (stages 1-5) ----------------
// actIn bf16 NHWC [8][HS][WS][CI]; wtr bf16 [9][CO][CI]; out bf16 NHWC [8][2HS][2WS][CO]
template <int CI, int CO, int HS, int WS>
__launch_bounds__(256)
__global__ void conv_stage_kernel(const __hip_bfloat16* __restrict__ actIn,
                                  const __hip_bfloat16* __restrict__ wtr,
                                  const float* __restrict__ S,
                                  __hip_bfloat16* __restrict__ actOut) {
    constexpr int HO = HS * 2, WO = WS * 2;
    const int tid = threadIdx.x;
    const int lane = tid & 63, wv = tid >> 6;
    const int tilesPerB = (HO * WO) / 64;
    const int b = blockIdx.x / tilesPerB;
    const int pix0 = (blockIdx.x % tilesPerB) * 64;
    const int n0 = blockIdx.y * 64;

    __shared__ alignas(16) __hip_bfloat16 Alds[64 * 32];
    __shared__ alignas(16) __hip_bfloat16 Blds[64 * 32];

    // staging roles: thread stages 8 ci for pixel/n-row sp
    const int sp = tid >> 2;
    const int soff = (tid & 3) * 8;
    const int gpix = pix0 + sp;
    const int h = gpix / WO;                 // WO power of two -> shifts
    const int w = gpix % WO;

    // wave quadrant: 32x32 per wave (2x2 of 16x16 MFMA tiles)
    const int mh = wv & 1, nh = wv >> 1;
    const int r = lane & 15, q = lane >> 4;

    f32x4 acc00 = {0.f, 0.f, 0.f, 0.f};
    f32x4 acc01 = {0.f, 0.f, 0.f, 0.f};
    f32x4 acc10 = {0.f, 0.f, 0.f, 0.f};
    f32x4 acc11 = {0.f, 0.f, 0.f, 0.f};

    #pragma unroll 1
    for (int tap = 0; tap < 9; ++tap) {
        const int u = h + tap / 3 - 1;
        const int v = w + tap % 3 - 1;
        const bool valid = (u >= 0) && (u < HO) && (v >= 0) && (v < WO);
        const int su = u >> 1, sv = v >> 1;  // nearest-2x upsample source
        const __hip_bfloat16* asrc = actIn + ((ptrdiff_t)((b * HS + su) * WS + sv) * CI + soff);
        const __hip_bfloat16* bsrc = wtr + ((size_t)tap * CO + n0 + sp) * CI + soff;
        for (int ci0 = 0; ci0 < CI; ci0 += 32) {
            uint4 av = {0, 0, 0, 0};
            if (valid) av = *(const uint4*)(asrc + ci0);
            uint4 bv = *(const uint4*)(bsrc + ci0);
            __syncthreads();
            *(uint4*)&Alds[sp * 32 + soff] = av;
            *(uint4*)&Blds[sp * 32 + soff] = bv;
            __syncthreads();
            bf16x8 a0 = *(const bf16x8*)&Alds[(mh * 32 + r) * 32 + q * 8];
            bf16x8 a1 = *(const bf16x8*)&Alds[(mh * 32 + 16 + r) * 32 + q * 8];
            bf16x8 b0 = *(const bf16x8*)&Blds[(nh * 32 + r) * 32 + q * 8];
            bf16x8 b1 = *(const bf16x8*)&Blds[(nh * 32 + 16 + r) * 32 + q * 8];
            acc00 = __builtin_amdgcn_mfma_f32_16x16x32_bf16(a0, b0, acc00, 0, 0, 0);
            acc01 = __builtin_amdgcn_mfma_f32_16x16x32_bf16(a0, b1, acc01, 0, 0, 0);
            acc10 = __builtin_amdgcn_mfma_f32_16x16x32_bf16(a1, b0, acc10, 0, 0, 0);
            acc11 = __builtin_amdgcn_mfma_f32_16x16x32_bf16(a1, b1, acc11, 0, 0, 0);
        }
    }

    // epilogue: C/D layout col=lane&15, row=(lane>>4)*4+reg (m89/m91)
    const int nA = n0 + nh * 32 + r;
    const int nB = nA + 16;
    const float s0 = S[b * CO + nA];
    const float s1 = S[b * CO + nB];
    #pragma unroll
    for (int i = 0; i < 2; ++i) {
        f32x4 vj0 = (i == 0) ? acc00 : acc10;
        f32x4 vj1 = (i == 0) ? acc01 : acc11;
        const int mbase = mh * 32 + i * 16 + q * 4;
        #pragma unroll
        for (int t2 = 0; t2 < 4; ++t2) {
            int gg = pix0 + mbase + t2;
            int hh = gg / WO, ww = gg % WO;
            size_t obase = ((size_t)(b * HO + hh) * WO + ww) * CO;
            actOut[obase + nA] = __float2bfloat16(fmaxf(vj0[t2] * s0, 0.f));
            actOut[obase + nB] = __float2bfloat16(fmaxf(vj1[t2] * s1, 0.f));
        }
    }
}

// ---------------- final conv: 64->3 at 256x256, +bias, fp32 NCHW out ----------------
__launch_bounds__(256)
__global__ void conv_final_kernel(const __hip_bfloat16* __restrict__ actIn, // [8][256][256][64]
                                  const __hip_bfloat16* __restrict__ wtr,  // [9][16][64]
                                  const float* __restrict__ bias,          // [3]
                                  float* __restrict__ out) {               // [8][3][256][256]
    constexpr int CI = 64, HO = 256, WO = 256;
    const int tid = threadIdx.x, lane = tid & 63, wv = tid >> 6;
    const int tilesPerB = (HO * WO) / 64;    // 1024
    const int b = blockIdx.x / tilesPerB;
    const int pix0 = (blockIdx.x % tilesPerB) * 64;

    __shared__ alignas(16) __hip_bfloat16 Alds[64 * 32];
    __shared__ alignas(16) __hip_bfloat16 Blds[16 * 32];

    const int sp = tid >> 2, soff = (tid & 3) * 8;
    const int gpix = pix0 + sp;
    const int h = gpix >> 8, w = gpix & 255;
    const int r = lane & 15, q = lane >> 4;

    f32x4 acc = {0.f, 0.f, 0.f, 0.f};

    #pragma unroll 1
    for (int tap = 0; tap < 9; ++tap) {
        const int u = h + tap / 3 - 1, v = w + tap % 3 - 1;
        const bool valid = (u >= 0) && (u < HO) && (v >= 0) && (v < WO);
        const __hip_bfloat16* asrc = actIn + ((ptrdiff_t)((b * HO + u) * WO + v) * CI + soff);
        const __hip_bfloat16* bsrc = wtr + ((size_t)tap * 16 + sp) * CI + soff; // only tid<64
        for (int ci0 = 0; ci0 < CI; ci0 += 32) {
            uint4 av = {0, 0, 0, 0};
            if (valid) av = *(const uint4*)(asrc + ci0);
            uint4 bv = {0, 0, 0, 0};
            if (tid < 64) bv = *(const uint4*)(bsrc + ci0);
            __syncthreads();
            *(uint4*)&Alds[sp * 32 + soff] = av;
            if (tid < 64) *(uint4*)&Blds[sp * 32 + soff] = bv;
            __syncthreads();
            bf16x8 a = *(const bf16x8*)&Alds[(wv * 16 + r) * 32 + q * 8];
            bf16x8 bb = *(const bf16x8*)&Blds[r * 32 + q * 8];
            acc = __builtin_amdgcn_mfma_f32_16x16x32_bf16(a, bb, acc, 0, 0, 0);
        }
    }

    if (r < 3) {
        float bs = bias[r];
        #pragma unroll
        for (int t2 = 0; t2 < 4; ++t2) {
            int gg = pix0 + wv * 16 + q * 4 + t2;
            int hh = gg >> 8, ww = gg & 255;
            out[((size_t)(b * 3 + r) << 16) + hh * 256 + ww] = acc[t2] + bs;
        }
    }
}

// ---------------- launch ----------------
extern "C" void kernel_launch(void* const* d_in, const int* in_sizes, int n_in,
                              void* d_out, int out_size, void* d_ws, size_t ws_size,
                              hipStream_t stream) {
    const float* x    = (const float*)d_in[0];
    const float* sty  = (const float*)d_in[1];
    const float* w1   = (const float*)d_in[2];
    const float* fw1  = (const float*)d_in[3];
    const float* fb1  = (const float*)d_in[4];
    const float* w2   = (const float*)d_in[5];
    const float* fw2  = (const float*)d_in[6];
    const float* fb2  = (const float*)d_in[7];
    const float* w3   = (const float*)d_in[8];
    const float* fw3  = (const float*)d_in[9];
    const float* fb3  = (const float*)d_in[10];
    const float* w4   = (const float*)d_in[11];
    const float* fw4  = (const float*)d_in[12];
    const float* fb4  = (const float*)d_in[13];
    const float* w5   = (const float*)d_in[14];
    const float* fw5  = (const float*)d_in[15];
    const float* fb5  = (const float*)d_in[16];
    const float* wf   = (const float*)d_in[17];
    const float* bf   = (const float*)d_in[18];
    float* out = (float*)d_out;

    char* ws = (char*)d_ws;
    size_t off = 0;
    auto alloc = [&](size_t bytes) {
        char* p = ws + off;
        off += (bytes + 255) & ~(size_t)255;
        return p;
    };
    float* S1 = (float*)alloc(8 * 256 * 4);
    float* S2 = (float*)alloc(8 * 128 * 4);
    float* S3 = (float*)alloc(8 * 64 * 4);
    float* S4 = (float*)alloc(8 * 64 * 4);
    float* S5 = (float*)alloc(8 * 64 * 4);
    __hip_bfloat16* act0 = (__hip_bfloat16*)alloc((size_t)262144 * 2);   // 8x8x8x512
    __hip_bfloat16* act1 = (__hip_bfloat16*)alloc((size_t)524288 * 2);   // 8x16x16x256
    __hip_bfloat16* act2 = (__hip_bfloat16*)alloc((size_t)1048576 * 2);  // 8x32x32x128
    __hip_bfloat16* act3 = (__hip_bfloat16*)alloc((size_t)2097152 * 2);  // 8x64x64x64
    __hip_bfloat16* act4 = (__hip_bfloat16*)alloc((size_t)8388608 * 2);  // 8x128x128x64
    __hip_bfloat16* act5 = (__hip_bfloat16*)alloc((size_t)33554432 * 2); // 8x256x256x64
    __hip_bfloat16* wt1  = (__hip_bfloat16*)alloc((size_t)9 * 256 * 512 * 2);
    __hip_bfloat16* wt2  = (__hip_bfloat16*)alloc((size_t)9 * 128 * 256 * 2);
    __hip_bfloat16* wt3  = (__hip_bfloat16*)alloc((size_t)9 * 64 * 128 * 2);
    __hip_bfloat16* wt4  = (__hip_bfloat16*)alloc((size_t)9 * 64 * 64 * 2);
    __hip_bfloat16* wt5  = (__hip_bfloat16*)alloc((size_t)9 * 64 * 64 * 2);
    __hip_bfloat16* wtF  = (__hip_bfloat16*)alloc((size_t)9 * 16 * 64 * 2);
    if (off > ws_size) return;  // workspace too small -> fail loudly via wrong output

    convert_x_kernel<<<1024, 256, 0, stream>>>(x, act0);
    wtrans_kernel<<<4608, 256, 0, stream>>>(w1, wt1, 256, 512);
    wtrans_kernel<<<1152, 256, 0, stream>>>(w2, wt2, 128, 256);
    wtrans_kernel<<<288, 256, 0, stream>>>(w3, wt3, 64, 128);
    wtrans_kernel<<<144, 256, 0, stream>>>(w4, wt4, 64, 64);
    wtrans_kernel<<<144, 256, 0, stream>>>(w5, wt5, 64, 64);
    wtrans_final_kernel<<<36, 256, 0, stream>>>(wf, wtF);
    style_fc_kernel<<<512, 256, 0, stream>>>(sty, fw1, fb1, S1, 256);
    style_fc_kernel<<<256, 256, 0, stream>>>(sty, fw2, fb2, S2, 128);
    style_fc_kernel<<<128, 256, 0, stream>>>(sty, fw3, fb3, S3, 64);
    style_fc_kernel<<<128, 256, 0, stream>>>(sty, fw4, fb4, S4, 64);
    style_fc_kernel<<<128, 256, 0, stream>>>(sty, fw5, fb5, S5, 64);

    conv_stage_kernel<512, 256, 8, 8><<<dim3(32, 4), 256, 0, stream>>>(act0, wt1, S1, act1);
    conv_stage_kernel<256, 128, 16, 16><<<dim3(128, 2), 256, 0, stream>>>(act1, wt2, S2, act2);
    conv_stage_kernel<128, 64, 32, 32><<<dim3(512, 1), 256, 0, stream>>>(act2, wt3, S3, act3);
    conv_stage_kernel<64, 64, 64, 64><<<dim3(2048, 1), 256, 0, stream>>>(act3, wt4, S4, act4);
    conv_stage_kernel<64, 64, 128, 128><<<dim3(8192, 1), 256, 0, stream>>>(act4, wt5, S5, act5);
    conv_final_kernel<<<8192, 256, 0, stream>>>(act5, wtF, bf, out);
}

// Round 2
// 313.180 us; speedup vs baseline: 1.1584x; 1.1584x over previous
//
#include <hip/hip_runtime.h>
#include <hip/hip_bf16.h>
#include <cstddef>

typedef __bf16 bf16x8 __attribute__((ext_vector_type(8)));
typedef float f32x4 __attribute__((ext_vector_type(4)));

// ---------------- prep kernels ----------------

// x fp32 NCHW [8,512,8,8] -> bf16 NHWC [8,8,8,512]
__global__ void convert_x_kernel(const float* __restrict__ x, __hip_bfloat16* __restrict__ act0) {
    int t = blockIdx.x * 256 + threadIdx.x;          // 262144 total
    int c = t & 511; int rest = t >> 9;
    int w = rest & 7; rest >>= 3; int h = rest & 7; int b = rest >> 3;
    act0[t] = __float2bfloat16(x[((b * 512 + c) * 8 + h) * 8 + w]);
}

// W fp32 [CO][CI][3][3] -> bf16 [9][CO][CI]
__global__ void wtrans_kernel(const float* __restrict__ w, __hip_bfloat16* __restrict__ o,
                              int CO, int CI) {
    int t = blockIdx.x * 256 + threadIdx.x;
    int total = 9 * CO * CI;
    if (t >= total) return;
    int ci = t % CI; int r2 = t / CI; int co = r2 % CO; int tap = r2 / CO;
    o[t] = __float2bfloat16(w[(co * CI + ci) * 9 + tap]);
}

// wf fp32 [3][64][3][3] -> bf16 [9][16][64], rows 3..15 zeroed
__global__ void wtrans_final_kernel(const float* __restrict__ w, __hip_bfloat16* __restrict__ o) {
    int t = blockIdx.x * 256 + threadIdx.x;          // 9216 total
    int ci = t & 63; int r2 = t >> 6; int co = r2 & 15; int tap = r2 >> 4;
    float v = (co < 3) ? w[(co * 64 + ci) * 9 + tap] : 0.f;
    o[t] = __float2bfloat16(v);
}

// S[b][o] = style[b,:] . fw[o,:] + fb[o]; one wave per (b,o)
__global__ void style_fc_kernel(const float* __restrict__ style, const float* __restrict__ fw,
                                const float* __restrict__ fb, float* __restrict__ S, int CO) {
    int wv = threadIdx.x >> 6, lane = threadIdx.x & 63;
    int idx = blockIdx.x * 4 + wv;
    int b = idx / CO, o = idx - b * CO;
    const float* sb = style + b * 512;
    const float* fwo = fw + o * 512;
    float p = 0.f;
    #pragma unroll
    for (int k = lane; k < 512; k += 64) p += sb[k] * fwo[k];
    #pragma unroll
    for (int off = 32; off > 0; off >>= 1) p += __shfl_down(p, off);
    if (lane == 0) S[idx] = p + fb[o];
}

// ---------------- patch-resident fused upsample+conv+scale+relu ----------------
// actIn bf16 NHWC [8][HS][WS][CI]; wtr bf16 [9][CO][CI]; out bf16 NHWC [8][2HS][2WS][CO]
// Block: 256 thr, computes a 16x16 output patch x 64 output channels (n0 = blockIdx.y*64).
// Input patch (10x10 src pixels x 64-ci slice, padded stride 72) staged once per ci-slice.
// Weights double-buffered per tap with register prefetch -> 1 barrier per tap.
template <int CI, int CO, int HS, int WS>
__launch_bounds__(256)
__global__ void conv_patch_kernel(const __hip_bfloat16* __restrict__ actIn,
                                  const __hip_bfloat16* __restrict__ wtr,
                                  const float* __restrict__ S,
                                  __hip_bfloat16* __restrict__ actOut) {
    constexpr int HO = HS * 2, WO = WS * 2;
    constexpr int CIH = CI / 64;       // 64-wide ci slices
    constexpr int KT = CIH * 9;        // total (ci-slice, tap) steps

    const int tid = threadIdx.x;
    const int lane = tid & 63, wv = tid >> 6;
    const int r = lane & 15, q = lane >> 4;

    const int pw = WO / 16, ppb = (HO / 16) * pw;
    const int b = blockIdx.x / ppb;
    const int prest = blockIdx.x - b * ppb;
    const int ph = prest / pw, pwi = prest - ph * pw;
    const int oh0 = ph * 16, ow0 = pwi * 16;
    const int sh0 = oh0 >> 1, sw0 = ow0 >> 1;   // tile covers src rows sh0-1 .. sh0+8
    const int n0 = blockIdx.y * 64;

    __shared__ alignas(16) __hip_bfloat16 Tile[100 * 72];     // 14400 B
    __shared__ alignas(16) __hip_bfloat16 Wlds[2][64 * 72];   // 2 x 9216 B

    f32x4 acc[4][4];
    #pragma unroll
    for (int i = 0; i < 4; ++i)
        #pragma unroll
        for (int j = 0; j < 4; ++j) acc[i][j] = f32x4{0.f, 0.f, 0.f, 0.f};

    const int wv4 = wv * 4;

    int cih = 0, tap = 0;
    #pragma unroll 1
    for (int kt = 0; kt < KT; ++kt) {
        if (tap == 0) {
            // stage input tile slice cih: 100 pixels x 64 ci
            for (int i = tid; i < 800; i += 256) {
                int pix = i >> 3, koct = i & 7;
                int tr = pix / 10, tc = pix - tr * 10;
                int su = sh0 - 1 + tr, sv = sw0 - 1 + tc;
                uint4 v = {0, 0, 0, 0};
                if (su >= 0 && su < HS && sv >= 0 && sv < WS)
                    v = *(const uint4*)(actIn +
                        ((size_t)((b * HS + su) * WS + sv) * CI + cih * 64 + koct * 8));
                *(uint4*)&Tile[pix * 72 + koct * 8] = v;
            }
            if (kt == 0) {
                // initial weight buffer
                for (int i = tid; i < 512; i += 256) {
                    int co = i >> 3, koct = i & 7;
                    *(uint4*)&Wlds[0][co * 72 + koct * 8] =
                        *(const uint4*)(wtr + ((size_t)0 * CO + n0 + co) * CI + koct * 8);
                }
            }
            __syncthreads();
        }

        // prefetch next step's weights into registers
        const bool pf = (kt + 1 < KT);
        uint4 wr0 = {0,0,0,0}, wr1 = {0,0,0,0};
        if (pf) {
            int tapn = (tap == 8) ? 0 : tap + 1;
            int cihn = (tap == 8) ? cih + 1 : cih;
            {
                int i = tid;          int co = i >> 3, koct = i & 7;
                wr0 = *(const uint4*)(wtr + ((size_t)tapn * CO + n0 + co) * CI + cihn * 64 + koct * 8);
            }
            {
                int i = tid + 256;    int co = i >> 3, koct = i & 7;
                wr1 = *(const uint4*)(wtr + ((size_t)tapn * CO + n0 + co) * CI + cihn * 64 + koct * 8);
            }
        }

        // A-frag tile-pixel indices for this tap (per-lane)
        const int dyv = tap / 3;
        const int dxm1 = tap - dyv * 3 - 1;
        const int tc = ((r + dxm1) >> 1) + 1;
        int apix[4];
        #pragma unroll
        for (int mt = 0; mt < 4; ++mt)
            apix[mt] = ((((wv4 + mt) + dyv - 1) >> 1) + 1) * 10 + tc;

        const int buf = kt & 1;
        #pragma unroll
        for (int ch = 0; ch < 2; ++ch) {
            bf16x8 af[4], bfr[4];
            #pragma unroll
            for (int mt = 0; mt < 4; ++mt)
                af[mt] = *(const bf16x8*)&Tile[apix[mt] * 72 + ch * 32 + q * 8];
            #pragma unroll
            for (int nt = 0; nt < 4; ++nt)
                bfr[nt] = *(const bf16x8*)&Wlds[buf][(nt * 16 + r) * 72 + ch * 32 + q * 8];
            #pragma unroll
            for (int mt = 0; mt < 4; ++mt)
                #pragma unroll
                for (int nt = 0; nt < 4; ++nt)
                    acc[mt][nt] = __builtin_amdgcn_mfma_f32_16x16x32_bf16(
                        af[mt], bfr[nt], acc[mt][nt], 0, 0, 0);
        }

        if (pf) {
            int nb = buf ^ 1;
            {
                int i = tid;       int co = i >> 3, koct = i & 7;
                *(uint4*)&Wlds[nb][co * 72 + koct * 8] = wr0;
            }
            {
                int i = tid + 256; int co = i >> 3, koct = i & 7;
                *(uint4*)&Wlds[nb][co * 72 + koct * 8] = wr1;
            }
            __syncthreads();
        }

        ++tap; if (tap == 9) { tap = 0; ++cih; }
    }

    // epilogue: C/D layout col(lane&15)=n, row(q*4+t2)=m
    float sv_[4];
    #pragma unroll
    for (int nt = 0; nt < 4; ++nt) sv_[nt] = S[b * CO + n0 + nt * 16 + r];
    #pragma unroll
    for (int mt = 0; mt < 4; ++mt) {
        const int prow = wv4 + mt;          // pixel row in patch
        #pragma unroll
        for (int t2 = 0; t2 < 4; ++t2) {
            const int pcol = q * 4 + t2;
            const size_t obase = ((size_t)(b * HO + oh0 + prow) * WO + ow0 + pcol) * CO + n0;
            #pragma unroll
            for (int nt = 0; nt < 4; ++nt)
                actOut[obase + nt * 16 + r] =
                    __float2bfloat16(fmaxf(acc[mt][nt][t2] * sv_[nt], 0.f));
        }
    }
}

// ---------------- final conv: 64->3 at 256x256, +bias, fp32 NCHW out ----------------
// Patch 8 rows x 16 cols (M=128); tile 10x18 src pixels x 64 ci; all 9 taps' weights resident.
__launch_bounds__(256)
__global__ void conv_final_kernel(const __hip_bfloat16* __restrict__ actIn, // [8][256][256][64]
                                  const __hip_bfloat16* __restrict__ wtr,  // [9][16][64]
                                  const float* __restrict__ bias,          // [3]
                                  float* __restrict__ out) {               // [8][3][256][256]
    constexpr int HO = 256, WO = 256;
    const int tid = threadIdx.x, lane = tid & 63, wv = tid >> 6;
    const int r = lane & 15, q = lane >> 4;

    // patches: 32 rows of 8 x 16 cols of 16 per batch
    const int ppb = 32 * 16;
    const int b = blockIdx.x / ppb;
    const int prest = blockIdx.x - b * ppb;
    const int ph = prest >> 4, pwi = prest & 15;
    const int oh0 = ph * 8, ow0 = pwi * 16;

    __shared__ alignas(16) __hip_bfloat16 Tile[10 * 18 * 72];   // 25920 B
    __shared__ alignas(16) __hip_bfloat16 Wl[9 * 16 * 72];      // 20736 B

    // stage tile: 180 pixels x 64 ci = 1440 uint4
    for (int i = tid; i < 1440; i += 256) {
        int pix = i >> 3, koct = i & 7;
        int tr = pix / 18, tc = pix - tr * 18;
        int u = oh0 - 1 + tr, v = ow0 - 1 + tc;
        uint4 val = {0, 0, 0, 0};
        if (u >= 0 && u < HO && v >= 0 && v < WO)
            val = *(const uint4*)(actIn + ((size_t)((b * HO + u) * WO + v) * 64 + koct * 8));
        *(uint4*)&Tile[pix * 72 + koct * 8] = val;
    }
    // stage all weights: 9*16 rows x 64 ci = 1152 octs
    for (int i = tid; i < 1152; i += 256) {
        int row = i >> 3, koct = i & 7;   // row = tap*16+co
        *(uint4*)&Wl[row * 72 + koct * 8] = *(const uint4*)(wtr + (size_t)row * 64 + koct * 8);
    }
    __syncthreads();

    f32x4 acc[2];
    acc[0] = f32x4{0.f, 0.f, 0.f, 0.f};
    acc[1] = f32x4{0.f, 0.f, 0.f, 0.f};

    #pragma unroll 1
    for (int tap = 0; tap < 9; ++tap) {
        const int dyv = tap / 3;
        const int dxv = tap - dyv * 3;
        const int tc = r + dxv;
        int apix[2];
        #pragma unroll
        for (int mt = 0; mt < 2; ++mt)
            apix[mt] = (wv * 2 + mt + dyv) * 18 + tc;
        #pragma unroll
        for (int ch = 0; ch < 2; ++ch) {
            bf16x8 bfr = *(const bf16x8*)&Wl[(tap * 16 + r) * 72 + ch * 32 + q * 8];
            #pragma unroll
            for (int mt = 0; mt < 2; ++mt) {
                bf16x8 af = *(const bf16x8*)&Tile[apix[mt] * 72 + ch * 32 + q * 8];
                acc[mt] = __builtin_amdgcn_mfma_f32_16x16x32_bf16(af, bfr, acc[mt], 0, 0, 0);
            }
        }
    }

    if (r < 3) {
        const float bs = bias[r];
        #pragma unroll
        for (int mt = 0; mt < 2; ++mt) {
            const int prow = wv * 2 + mt;
            #pragma unroll
            for (int t2 = 0; t2 < 4; ++t2) {
                const int pcol = q * 4 + t2;
                out[((size_t)(b * 3 + r) << 16) + (oh0 + prow) * 256 + ow0 + pcol] =
                    acc[mt][t2] + bs;
            }
        }
    }
}

// ---------------- launch ----------------
extern "C" void kernel_launch(void* const* d_in, const int* in_sizes, int n_in,
                              void* d_out, int out_size, void* d_ws, size_t ws_size,
                              hipStream_t stream) {
    const float* x    = (const float*)d_in[0];
    const float* sty  = (const float*)d_in[1];
    const float* w1   = (const float*)d_in[2];
    const float* fw1  = (const float*)d_in[3];
    const float* fb1  = (const float*)d_in[4];
    const float* w2   = (const float*)d_in[5];
    const float* fw2  = (const float*)d_in[6];
    const float* fb2  = (const float*)d_in[7];
    const float* w3   = (const float*)d_in[8];
    const float* fw3  = (const float*)d_in[9];
    const float* fb3  = (const float*)d_in[10];
    const float* w4   = (const float*)d_in[11];
    const float* fw4  = (const float*)d_in[12];
    const float* fb4  = (const float*)d_in[13];
    const float* w5   = (const float*)d_in[14];
    const float* fw5  = (const float*)d_in[15];
    const float* fb5  = (const float*)d_in[16];
    const float* wf   = (const float*)d_in[17];
    const float* bf   = (const float*)d_in[18];
    float* out = (float*)d_out;

    char* ws = (char*)d_ws;
    size_t off = 0;
    auto alloc = [&](size_t bytes) {
        char* p = ws + off;
        off += (bytes + 255) & ~(size_t)255;
        return p;
    };
    float* S1 = (float*)alloc(8 * 256 * 4);
    float* S2 = (float*)alloc(8 * 128 * 4);
    float* S3 = (float*)alloc(8 * 64 * 4);
    float* S4 = (float*)alloc(8 * 64 * 4);
    float* S5 = (float*)alloc(8 * 64 * 4);
    __hip_bfloat16* act0 = (__hip_bfloat16*)alloc((size_t)262144 * 2);   // 8x8x8x512
    __hip_bfloat16* act1 = (__hip_bfloat16*)alloc((size_t)524288 * 2);   // 8x16x16x256
    __hip_bfloat16* act2 = (__hip_bfloat16*)alloc((size_t)1048576 * 2);  // 8x32x32x128
    __hip_bfloat16* act3 = (__hip_bfloat16*)alloc((size_t)2097152 * 2);  // 8x64x64x64
    __hip_bfloat16* act4 = (__hip_bfloat16*)alloc((size_t)8388608 * 2);  // 8x128x128x64
    __hip_bfloat16* act5 = (__hip_bfloat16*)alloc((size_t)33554432 * 2); // 8x256x256x64
    __hip_bfloat16* wt1  = (__hip_bfloat16*)alloc((size_t)9 * 256 * 512 * 2);
    __hip_bfloat16* wt2  = (__hip_bfloat16*)alloc((size_t)9 * 128 * 256 * 2);
    __hip_bfloat16* wt3  = (__hip_bfloat16*)alloc((size_t)9 * 64 * 128 * 2);
    __hip_bfloat16* wt4  = (__hip_bfloat16*)alloc((size_t)9 * 64 * 64 * 2);
    __hip_bfloat16* wt5  = (__hip_bfloat16*)alloc((size_t)9 * 64 * 64 * 2);
    __hip_bfloat16* wtF  = (__hip_bfloat16*)alloc((size_t)9 * 16 * 64 * 2);
    if (off > ws_size) return;

    convert_x_kernel<<<1024, 256, 0, stream>>>(x, act0);
    wtrans_kernel<<<4608, 256, 0, stream>>>(w1, wt1, 256, 512);
    wtrans_kernel<<<1152, 256, 0, stream>>>(w2, wt2, 128, 256);
    wtrans_kernel<<<288, 256, 0, stream>>>(w3, wt3, 64, 128);
    wtrans_kernel<<<144, 256, 0, stream>>>(w4, wt4, 64, 64);
    wtrans_kernel<<<144, 256, 0, stream>>>(w5, wt5, 64, 64);
    wtrans_final_kernel<<<36, 256, 0, stream>>>(wf, wtF);
    style_fc_kernel<<<512, 256, 0, stream>>>(sty, fw1, fb1, S1, 256);
    style_fc_kernel<<<256, 256, 0, stream>>>(sty, fw2, fb2, S2, 128);
    style_fc_kernel<<<128, 256, 0, stream>>>(sty, fw3, fb3, S3, 64);
    style_fc_kernel<<<128, 256, 0, stream>>>(sty, fw4, fb4, S4, 64);
    style_fc_kernel<<<128, 256, 0, stream>>>(sty, fw5, fb5, S5, 64);

    // patch kernel: grid.x = 8 * (HO/16)*(WO/16), grid.y = CO/64
    conv_patch_kernel<512, 256, 8, 8><<<dim3(8, 4), 256, 0, stream>>>(act0, wt1, S1, act1);
    conv_patch_kernel<256, 128, 16, 16><<<dim3(32, 2), 256, 0, stream>>>(act1, wt2, S2, act2);
    conv_patch_kernel<128, 64, 32, 32><<<dim3(128, 1), 256, 0, stream>>>(act2, wt3, S3, act3);
    conv_patch_kernel<64, 64, 64, 64><<<dim3(512, 1), 256, 0, stream>>>(act3, wt4, S4, act4);
    conv_patch_kernel<64, 64, 128, 128><<<dim3(2048, 1), 256, 0, stream>>>(act4, wt5, S5, act5);
    conv_final_kernel<<<4096, 256, 0, stream>>>(act5, wtF, bf, out);
}

// Round 3
// 244.897 us; speedup vs baseline: 1.4814x; 1.2788x over previous
//
#include <hip/hip_runtime.h>
#include <hip/hip_bf16.h>
#include <cstddef>

typedef __bf16 bf16x8 __attribute__((ext_vector_type(8)));
typedef float f32x4 __attribute__((ext_vector_type(4)));

// ---------------- prep kernels ----------------

// x fp32 NCHW [8,512,8,8] -> bf16 NHWC [8,8,8,512]
__global__ void convert_x_kernel(const float* __restrict__ x, __hip_bfloat16* __restrict__ act0) {
    int t = blockIdx.x * 256 + threadIdx.x;          // 262144 total
    int c = t & 511; int rest = t >> 9;
    int w = rest & 7; rest >>= 3; int h = rest & 7; int b = rest >> 3;
    act0[t] = __float2bfloat16(x[((b * 512 + c) * 8 + h) * 8 + w]);
}

// All weight transposes fused: fp32 [CO][CI][3][3] -> bf16 [9][CO][CI] (x5) + final (CO padded 3->16)
__global__ void wtrans_all_kernel(const float* __restrict__ w1, __hip_bfloat16* __restrict__ o1,
                                  const float* __restrict__ w2, __hip_bfloat16* __restrict__ o2,
                                  const float* __restrict__ w3, __hip_bfloat16* __restrict__ o3,
                                  const float* __restrict__ w4, __hip_bfloat16* __restrict__ o4,
                                  const float* __restrict__ w5, __hip_bfloat16* __restrict__ o5,
                                  const float* __restrict__ wf, __hip_bfloat16* __restrict__ of) {
    int t = blockIdx.x * 256 + threadIdx.x;
    const float* w; __hip_bfloat16* o; int lgci, lgco; bool fin = false;
    if      (t < 1179648) { w = w1; o = o1; lgci = 9; lgco = 8; }
    else if (t < 1474560) { t -= 1179648; w = w2; o = o2; lgci = 8; lgco = 7; }
    else if (t < 1548288) { t -= 1474560; w = w3; o = o3; lgci = 7; lgco = 6; }
    else if (t < 1585152) { t -= 1548288; w = w4; o = o4; lgci = 6; lgco = 6; }
    else if (t < 1622016) { t -= 1585152; w = w5; o = o5; lgci = 6; lgco = 6; }
    else if (t < 1631232) { t -= 1622016; w = wf; o = of; lgci = 6; lgco = 4; fin = true; }
    else return;
    int CI = 1 << lgci;
    int ci = t & (CI - 1);
    int co = (t >> lgci) & ((1 << lgco) - 1);
    int tap = t >> (lgci + lgco);
    float v = 0.f;
    if (!fin || co < 3) v = w[((size_t)co * CI + ci) * 9 + tap];
    o[t] = __float2bfloat16(v);
}

// All style FCs fused. S laid out contiguously: S1@0 (8x256), S2@2048 (8x128),
// S3@3072, S4@3584, S5@4096 (8x64 each). One wave per (stage,b,o) -> 4608 waves.
__global__ void style_all_kernel(const float* __restrict__ style,
                                 const float* __restrict__ fw1, const float* __restrict__ fb1,
                                 const float* __restrict__ fw2, const float* __restrict__ fb2,
                                 const float* __restrict__ fw3, const float* __restrict__ fb3,
                                 const float* __restrict__ fw4, const float* __restrict__ fb4,
                                 const float* __restrict__ fw5, const float* __restrict__ fb5,
                                 float* __restrict__ S) {
    int wvid = blockIdx.x * 4 + (threadIdx.x >> 6);
    int lane = threadIdx.x & 63;
    const float* fw; const float* fb; int lg, sOff, local;
    if      (wvid < 2048) { fw = fw1; fb = fb1; lg = 8; sOff = 0;    local = wvid; }
    else if (wvid < 3072) { fw = fw2; fb = fb2; lg = 7; sOff = 2048; local = wvid - 2048; }
    else if (wvid < 3584) { fw = fw3; fb = fb3; lg = 6; sOff = 3072; local = wvid - 3072; }
    else if (wvid < 4096) { fw = fw4; fb = fb4; lg = 6; sOff = 3584; local = wvid - 3584; }
    else                  { fw = fw5; fb = fb5; lg = 6; sOff = 4096; local = wvid - 4096; }
    int b = local >> lg, o = local & ((1 << lg) - 1);
    const float* sb = style + b * 512;
    const float* fwo = fw + (size_t)o * 512;
    float p = 0.f;
    #pragma unroll
    for (int k = lane; k < 512; k += 64) p += sb[k] * fwo[k];
    #pragma unroll
    for (int off = 32; off > 0; off >>= 1) p += __shfl_down(p, off);
    if (lane == 0) S[sOff + local] = p + fb[o];
}

// ---------------- K-split partial conv (stages 1-3) ----------------
// Each block: 16x16 output patch x 64 co x one 64-ci slice (blockIdx.z); fp32 partials.
template <int CI, int CO, int HS, int WS>
__launch_bounds__(256)
__global__ void conv_partial_kernel(const __hip_bfloat16* __restrict__ actIn,
                                    const __hip_bfloat16* __restrict__ wtr,
                                    float* __restrict__ Part) {
    constexpr int HO = HS * 2, WO = WS * 2;
    constexpr size_t sliceN = (size_t)8 * HO * WO * CO;
    const int tid = threadIdx.x;
    const int lane = tid & 63, wv = tid >> 6;
    const int r = lane & 15, q = lane >> 4;
    const int pw = WO / 16, ppb = (HO / 16) * pw;
    const int b = blockIdx.x / ppb;
    const int prest = blockIdx.x - b * ppb;
    const int ph = prest / pw, pwi = prest - ph * pw;
    const int oh0 = ph * 16, ow0 = pwi * 16;
    const int sh0 = oh0 >> 1, sw0 = ow0 >> 1;
    const int n0 = blockIdx.y * 64;
    const int ciOff = blockIdx.z * 64;

    __shared__ alignas(16) __hip_bfloat16 Tile[100 * 72];
    __shared__ alignas(16) __hip_bfloat16 Wlds[2][64 * 72];

    f32x4 acc[4][4];
    #pragma unroll
    for (int i = 0; i < 4; ++i)
        #pragma unroll
        for (int j = 0; j < 4; ++j) acc[i][j] = f32x4{0.f, 0.f, 0.f, 0.f};

    // stage A tile (100 px x 64 ci, padded stride 72)
    for (int i = tid; i < 800; i += 256) {
        int pix = i >> 3, koct = i & 7;
        int tr = pix / 10, tc2 = pix - tr * 10;
        int su = sh0 - 1 + tr, sv = sw0 - 1 + tc2;
        uint4 v = {0, 0, 0, 0};
        if (su >= 0 && su < HS && sv >= 0 && sv < WS)
            v = *(const uint4*)(actIn + ((size_t)((b * HS + su) * WS + sv) * CI + ciOff + koct * 8));
        *(uint4*)&Tile[pix * 72 + koct * 8] = v;
    }
    // stage tap-0 weights
    for (int i = tid; i < 512; i += 256) {
        int co = i >> 3, koct = i & 7;
        *(uint4*)&Wlds[0][co * 72 + koct * 8] =
            *(const uint4*)(wtr + ((size_t)(n0 + co)) * CI + ciOff + koct * 8);
    }
    __syncthreads();

    #pragma unroll 1
    for (int tap = 0; tap < 9; ++tap) {
        const bool pf = (tap < 8);
        uint4 wr0 = {0,0,0,0}, wr1 = {0,0,0,0};
        if (pf) {
            int co0 = tid >> 3, k0 = tid & 7;
            wr0 = *(const uint4*)(wtr + ((size_t)(tap + 1) * CO + n0 + co0) * CI + ciOff + k0 * 8);
            int i1 = tid + 256; int co1 = i1 >> 3, k1 = i1 & 7;
            wr1 = *(const uint4*)(wtr + ((size_t)(tap + 1) * CO + n0 + co1) * CI + ciOff + k1 * 8);
        }
        const int dyv = tap / 3;
        const int dxm1 = tap - dyv * 3 - 1;
        const int tc = ((r + dxm1) >> 1) + 1;
        int apix[4];
        #pragma unroll
        for (int mt = 0; mt < 4; ++mt)
            apix[mt] = ((((wv * 4 + mt) + dyv - 1) >> 1) + 1) * 10 + tc;

        const int buf = tap & 1;
        #pragma unroll
        for (int ch = 0; ch < 2; ++ch) {
            bf16x8 af[4], bfr[4];
            #pragma unroll
            for (int mt = 0; mt < 4; ++mt)
                af[mt] = *(const bf16x8*)&Tile[apix[mt] * 72 + ch * 32 + q * 8];
            #pragma unroll
            for (int nt = 0; nt < 4; ++nt)
                bfr[nt] = *(const bf16x8*)&Wlds[buf][(nt * 16 + r) * 72 + ch * 32 + q * 8];
            #pragma unroll
            for (int mt = 0; mt < 4; ++mt)
                #pragma unroll
                for (int nt = 0; nt < 4; ++nt)
                    acc[mt][nt] = __builtin_amdgcn_mfma_f32_16x16x32_bf16(
                        af[mt], bfr[nt], acc[mt][nt], 0, 0, 0);
        }
        if (pf) {
            int nb = buf ^ 1;
            { int co0 = tid >> 3, k0 = tid & 7;
              *(uint4*)&Wlds[nb][co0 * 72 + k0 * 8] = wr0; }
            { int i1 = tid + 256; int co1 = i1 >> 3, k1 = i1 & 7;
              *(uint4*)&Wlds[nb][co1 * 72 + k1 * 8] = wr1; }
            __syncthreads();
        }
    }

    // fp32 partial write, NHWC within slice
    float* P = Part + (size_t)blockIdx.z * sliceN;
    #pragma unroll
    for (int mt = 0; mt < 4; ++mt) {
        const int prow = wv * 4 + mt;
        #pragma unroll
        for (int t2 = 0; t2 < 4; ++t2) {
            const int pcol = q * 4 + t2;
            const size_t obase = ((size_t)(b * HO + oh0 + prow) * WO + ow0 + pcol) * CO + n0;
            #pragma unroll
            for (int nt = 0; nt < 4; ++nt)
                P[obase + nt * 16 + r] = acc[mt][nt][t2];
        }
    }
}

// sum KS fp32 partial slices -> scale + relu -> bf16 NHWC
template <int KS, int CO, int HW>
__launch_bounds__(256)
__global__ void reduce_kernel(const float* __restrict__ Part, const float* __restrict__ S,
                              __hip_bfloat16* __restrict__ actOut) {
    constexpr size_t sliceN = (size_t)8 * HW * CO;
    size_t e = ((size_t)blockIdx.x * 256 + threadIdx.x) * 4;
    if (e >= sliceN) return;
    f32x4 sum = {0.f, 0.f, 0.f, 0.f};
    #pragma unroll
    for (int k = 0; k < KS; ++k) sum += *(const f32x4*)(Part + (size_t)k * sliceN + e);
    const int co = (int)(e & (CO - 1));
    const int b = (int)(e / ((size_t)HW * CO));
    const float* Sb = S + b * CO + co;
    union { ushort4 u; __hip_bfloat16 h[4]; } pack;
    #pragma unroll
    for (int j = 0; j < 4; ++j)
        pack.h[j] = __float2bfloat16(fmaxf(sum[j] * Sb[j], 0.f));
    *(ushort4*)((unsigned short*)actOut + e) = pack.u;
}

// ---------------- patch-resident fused conv (stages 4-5, KS=1) ----------------
template <int CI, int CO, int HS, int WS>
__launch_bounds__(256)
__global__ void conv_patch_kernel(const __hip_bfloat16* __restrict__ actIn,
                                  const __hip_bfloat16* __restrict__ wtr,
                                  const float* __restrict__ S,
                                  __hip_bfloat16* __restrict__ actOut) {
    constexpr int HO = HS * 2, WO = WS * 2;
    constexpr int CIH = CI / 64;
    constexpr int KT = CIH * 9;

    const int tid = threadIdx.x;
    const int lane = tid & 63, wv = tid >> 6;
    const int r = lane & 15, q = lane >> 4;

    const int pw = WO / 16, ppb = (HO / 16) * pw;
    const int b = blockIdx.x / ppb;
    const int prest = blockIdx.x - b * ppb;
    const int ph = prest / pw, pwi = prest - ph * pw;
    const int oh0 = ph * 16, ow0 = pwi * 16;
    const int sh0 = oh0 >> 1, sw0 = ow0 >> 1;
    const int n0 = blockIdx.y * 64;

    __shared__ alignas(16) __hip_bfloat16 Tile[100 * 72];
    __shared__ alignas(16) __hip_bfloat16 Wlds[2][64 * 72];

    f32x4 acc[4][4];
    #pragma unroll
    for (int i = 0; i < 4; ++i)
        #pragma unroll
        for (int j = 0; j < 4; ++j) acc[i][j] = f32x4{0.f, 0.f, 0.f, 0.f};

    const int wv4 = wv * 4;

    int cih = 0, tap = 0;
    #pragma unroll 1
    for (int kt = 0; kt < KT; ++kt) {
        if (tap == 0) {
            for (int i = tid; i < 800; i += 256) {
                int pix = i >> 3, koct = i & 7;
                int tr = pix / 10, tc2 = pix - tr * 10;
                int su = sh0 - 1 + tr, sv = sw0 - 1 + tc2;
                uint4 v = {0, 0, 0, 0};
                if (su >= 0 && su < HS && sv >= 0 && sv < WS)
                    v = *(const uint4*)(actIn +
                        ((size_t)((b * HS + su) * WS + sv) * CI + cih * 64 + koct * 8));
                *(uint4*)&Tile[pix * 72 + koct * 8] = v;
            }
            if (kt == 0) {
                for (int i = tid; i < 512; i += 256) {
                    int co = i >> 3, koct = i & 7;
                    *(uint4*)&Wlds[0][co * 72 + koct * 8] =
                        *(const uint4*)(wtr + ((size_t)(n0 + co)) * CI + koct * 8);
                }
            }
            __syncthreads();
        }

        const bool pf = (kt + 1 < KT);
        uint4 wr0 = {0,0,0,0}, wr1 = {0,0,0,0};
        if (pf) {
            int tapn = (tap == 8) ? 0 : tap + 1;
            int cihn = (tap == 8) ? cih + 1 : cih;
            { int co0 = tid >> 3, k0 = tid & 7;
              wr0 = *(const uint4*)(wtr + ((size_t)tapn * CO + n0 + co0) * CI + cihn * 64 + k0 * 8); }
            { int i1 = tid + 256; int co1 = i1 >> 3, k1 = i1 & 7;
              wr1 = *(const uint4*)(wtr + ((size_t)tapn * CO + n0 + co1) * CI + cihn * 64 + k1 * 8); }
        }

        const int dyv = tap / 3;
        const int dxm1 = tap - dyv * 3 - 1;
        const int tc = ((r + dxm1) >> 1) + 1;
        int apix[4];
        #pragma unroll
        for (int mt = 0; mt < 4; ++mt)
            apix[mt] = ((((wv4 + mt) + dyv - 1) >> 1) + 1) * 10 + tc;

        const int buf = kt & 1;
        #pragma unroll
        for (int ch = 0; ch < 2; ++ch) {
            bf16x8 af[4], bfr[4];
            #pragma unroll
            for (int mt = 0; mt < 4; ++mt)
                af[mt] = *(const bf16x8*)&Tile[apix[mt] * 72 + ch * 32 + q * 8];
            #pragma unroll
            for (int nt = 0; nt < 4; ++nt)
                bfr[nt] = *(const bf16x8*)&Wlds[buf][(nt * 16 + r) * 72 + ch * 32 + q * 8];
            #pragma unroll
            for (int mt = 0; mt < 4; ++mt)
                #pragma unroll
                for (int nt = 0; nt < 4; ++nt)
                    acc[mt][nt] = __builtin_amdgcn_mfma_f32_16x16x32_bf16(
                        af[mt], bfr[nt], acc[mt][nt], 0, 0, 0);
        }

        if (pf) {
            int nb = buf ^ 1;
            { int co0 = tid >> 3, k0 = tid & 7;
              *(uint4*)&Wlds[nb][co0 * 72 + k0 * 8] = wr0; }
            { int i1 = tid + 256; int co1 = i1 >> 3, k1 = i1 & 7;
              *(uint4*)&Wlds[nb][co1 * 72 + k1 * 8] = wr1; }
            __syncthreads();
        }

        ++tap; if (tap == 9) { tap = 0; ++cih; }
    }

    float sv_[4];
    #pragma unroll
    for (int nt = 0; nt < 4; ++nt) sv_[nt] = S[b * CO + n0 + nt * 16 + r];
    #pragma unroll
    for (int mt = 0; mt < 4; ++mt) {
        const int prow = wv4 + mt;
        #pragma unroll
        for (int t2 = 0; t2 < 4; ++t2) {
            const int pcol = q * 4 + t2;
            const size_t obase = ((size_t)(b * HO + oh0 + prow) * WO + ow0 + pcol) * CO + n0;
            #pragma unroll
            for (int nt = 0; nt < 4; ++nt)
                actOut[obase + nt * 16 + r] =
                    __float2bfloat16(fmaxf(acc[mt][nt][t2] * sv_[nt], 0.f));
        }
    }
}

// ---------------- final conv: 64->3 at 256x256, +bias, fp32 NCHW out ----------------
__launch_bounds__(256)
__global__ void conv_final_kernel(const __hip_bfloat16* __restrict__ actIn, // [8][256][256][64]
                                  const __hip_bfloat16* __restrict__ wtr,  // [9][16][64]
                                  const float* __restrict__ bias,
                                  float* __restrict__ out) {               // [8][3][256][256]
    constexpr int HO = 256, WO = 256;
    const int tid = threadIdx.x, lane = tid & 63, wv = tid >> 6;
    const int r = lane & 15, q = lane >> 4;

    const int ppb = 32 * 16;
    const int b = blockIdx.x / ppb;
    const int prest = blockIdx.x - b * ppb;
    const int ph = prest >> 4, pwi = prest & 15;
    const int oh0 = ph * 8, ow0 = pwi * 16;

    __shared__ alignas(16) __hip_bfloat16 Tile[10 * 18 * 72];
    __shared__ alignas(16) __hip_bfloat16 Wl[9 * 16 * 72];

    for (int i = tid; i < 1440; i += 256) {
        int pix = i >> 3, koct = i & 7;
        int tr = pix / 18, tc2 = pix - tr * 18;
        int u = oh0 - 1 + tr, v = ow0 - 1 + tc2;
        uint4 val = {0, 0, 0, 0};
        if (u >= 0 && u < HO && v >= 0 && v < WO)
            val = *(const uint4*)(actIn + ((size_t)((b * HO + u) * WO + v) * 64 + koct * 8));
        *(uint4*)&Tile[pix * 72 + koct * 8] = val;
    }
    for (int i = tid; i < 1152; i += 256) {
        int row = i >> 3, koct = i & 7;
        *(uint4*)&Wl[row * 72 + koct * 8] = *(const uint4*)(wtr + (size_t)row * 64 + koct * 8);
    }
    __syncthreads();

    f32x4 acc[2];
    acc[0] = f32x4{0.f, 0.f, 0.f, 0.f};
    acc[1] = f32x4{0.f, 0.f, 0.f, 0.f};

    #pragma unroll 1
    for (int tap = 0; tap < 9; ++tap) {
        const int dyv = tap / 3;
        const int dxv = tap - dyv * 3;
        const int tc = r + dxv;
        int apix[2];
        #pragma unroll
        for (int mt = 0; mt < 2; ++mt)
            apix[mt] = (wv * 2 + mt + dyv) * 18 + tc;
        #pragma unroll
        for (int ch = 0; ch < 2; ++ch) {
            bf16x8 bfr = *(const bf16x8*)&Wl[(tap * 16 + r) * 72 + ch * 32 + q * 8];
            #pragma unroll
            for (int mt = 0; mt < 2; ++mt) {
                bf16x8 af = *(const bf16x8*)&Tile[apix[mt] * 72 + ch * 32 + q * 8];
                acc[mt] = __builtin_amdgcn_mfma_f32_16x16x32_bf16(af, bfr, acc[mt], 0, 0, 0);
            }
        }
    }

    if (r < 3) {
        const float bs = bias[r];
        #pragma unroll
        for (int mt = 0; mt < 2; ++mt) {
            const int prow = wv * 2 + mt;
            #pragma unroll
            for (int t2 = 0; t2 < 4; ++t2) {
                const int pcol = q * 4 + t2;
                out[((size_t)(b * 3 + r) << 16) + (oh0 + prow) * 256 + ow0 + pcol] =
                    acc[mt][t2] + bs;
            }
        }
    }
}

// ---------------- launch ----------------
extern "C" void kernel_launch(void* const* d_in, const int* in_sizes, int n_in,
                              void* d_out, int out_size, void* d_ws, size_t ws_size,
                              hipStream_t stream) {
    const float* x    = (const float*)d_in[0];
    const float* sty  = (const float*)d_in[1];
    const float* w1   = (const float*)d_in[2];
    const float* fw1  = (const float*)d_in[3];
    const float* fb1  = (const float*)d_in[4];
    const float* w2   = (const float*)d_in[5];
    const float* fw2  = (const float*)d_in[6];
    const float* fb2  = (const float*)d_in[7];
    const float* w3   = (const float*)d_in[8];
    const float* fw3  = (const float*)d_in[9];
    const float* fb3  = (const float*)d_in[10];
    const float* w4   = (const float*)d_in[11];
    const float* fw4  = (const float*)d_in[12];
    const float* fb4  = (const float*)d_in[13];
    const float* w5   = (const float*)d_in[14];
    const float* fw5  = (const float*)d_in[15];
    const float* fb5  = (const float*)d_in[16];
    const float* wf   = (const float*)d_in[17];
    const float* bf   = (const float*)d_in[18];
    float* out = (float*)d_out;

    char* ws = (char*)d_ws;
    size_t off = 0;
    auto alloc = [&](size_t bytes) {
        char* p = ws + off;
        off += (bytes + 255) & ~(size_t)255;
        return p;
    };
    // S1..S5 contiguous (all sizes multiples of 256 B) -> fused style kernel writes S1 base
    float* S1 = (float*)alloc(8 * 256 * 4);
    float* S2 = (float*)alloc(8 * 128 * 4);
    float* S3 = (float*)alloc(8 * 64 * 4);
    float* S4 = (float*)alloc(8 * 64 * 4);
    float* S5 = (float*)alloc(8 * 64 * 4);
    __hip_bfloat16* act0 = (__hip_bfloat16*)alloc((size_t)262144 * 2);   // 8x8x8x512
    __hip_bfloat16* act1 = (__hip_bfloat16*)alloc((size_t)524288 * 2);   // 8x16x16x256
    __hip_bfloat16* act2 = (__hip_bfloat16*)alloc((size_t)1048576 * 2);  // 8x32x32x128
    __hip_bfloat16* act3 = (__hip_bfloat16*)alloc((size_t)2097152 * 2);  // 8x64x64x64
    __hip_bfloat16* act4 = (__hip_bfloat16*)alloc((size_t)8388608 * 2);  // 8x128x128x64
    __hip_bfloat16* act5 = (__hip_bfloat16*)alloc((size_t)33554432 * 2); // 8x256x256x64
    __hip_bfloat16* wt1  = (__hip_bfloat16*)alloc((size_t)9 * 256 * 512 * 2);
    __hip_bfloat16* wt2  = (__hip_bfloat16*)alloc((size_t)9 * 128 * 256 * 2);
    __hip_bfloat16* wt3  = (__hip_bfloat16*)alloc((size_t)9 * 64 * 128 * 2);
    __hip_bfloat16* wt4  = (__hip_bfloat16*)alloc((size_t)9 * 64 * 64 * 2);
    __hip_bfloat16* wt5  = (__hip_bfloat16*)alloc((size_t)9 * 64 * 64 * 2);
    __hip_bfloat16* wtF  = (__hip_bfloat16*)alloc((size_t)9 * 16 * 64 * 2);
    if (off > ws_size) return;

    // fp32 K-split partial scratch (16 MB) aliased onto act5 (64 MB, written only by
    // stage 5 which runs after the last reduce) -- no extra ws footprint.
    float* Part = (float*)act5;

    convert_x_kernel<<<1024, 256, 0, stream>>>(x, act0);
    wtrans_all_kernel<<<6372, 256, 0, stream>>>(w1, wt1, w2, wt2, w3, wt3,
                                                w4, wt4, w5, wt5, wf, wtF);
    style_all_kernel<<<1152, 256, 0, stream>>>(sty, fw1, fb1, fw2, fb2, fw3, fb3,
                                               fw4, fb4, fw5, fb5, S1);

    // stages 1-3: K-split partials (256 blocks each) + reduce
    conv_partial_kernel<512, 256, 8, 8><<<dim3(8, 4, 8), 256, 0, stream>>>(act0, wt1, Part);
    reduce_kernel<8, 256, 256><<<512, 256, 0, stream>>>(Part, S1, act1);
    conv_partial_kernel<256, 128, 16, 16><<<dim3(32, 2, 4), 256, 0, stream>>>(act1, wt2, Part);
    reduce_kernel<4, 128, 1024><<<1024, 256, 0, stream>>>(Part, S2, act2);
    conv_partial_kernel<128, 64, 32, 32><<<dim3(128, 1, 2), 256, 0, stream>>>(act2, wt3, Part);
    reduce_kernel<2, 64, 4096><<<2048, 256, 0, stream>>>(Part, S3, act3);

    // stages 4-5: fused patch kernel (enough blocks already)
    conv_patch_kernel<64, 64, 64, 64><<<dim3(512, 1), 256, 0, stream>>>(act3, wt4, S4, act4);
    conv_patch_kernel<64, 64, 128, 128><<<dim3(2048, 1), 256, 0, stream>>>(act4, wt5, S5, act5);
    conv_final_kernel<<<4096, 256, 0, stream>>>(act5, wtF, bf, out);
}